// Round 6
// baseline (166.134 us; speedup 1.0000x reference)
//
#include <hip/hip_runtime.h>
#include <math.h>

// RX gate on qubit 10 of a 22-qubit state, batch=4. Output = REAL PART only
// (fp32, 2^24 elems), verified (absmax 0.0156).
//
// Key identity (R6): for output f32x4-vector v = (a*2+j)*2048 + c,
//     out[v] = c[b]*re[v] + s[b]*im[v ^ 2048]
// works for BOTH j=0 and j=1 (partner is v^2048 in vector units, sign +s
// both ways). No pairing, no branch: each thread = 2 loads + 1 store, each
// wave = 3 contiguous 1 KiB streams — the exact shape of the 6.29 TB/s
// copy ubench.
//
// Session ledger:
//  R2 (4 pairs/thread, nt): kernel 41.5 us, FETCH=64 MiB WRITE=64 MiB.
//  R3 (plain loads): 61 us, FETCH UNCHANGED -> L3 residency is harness-set;
//     nt loads = 1.5x throughput via L2 bypass. KEEP nt loads.
//  R4 (1 pair/thread): ~39.5 us (below the 40.4 us fill kernels; e2e 163.6).
//     201 MB fabric / 39.5 us = 5.1 TB/s = 81% of copy ceiling.
//  R5 (2 pairs/thread): ~40 us, e2e 164.2 — NEUTRAL/slightly worse.
//     Trend: LIGHTER waves with FEWER streams trend better (41.5->40->39.5).
//  R6 (this): minimal-wave copy-shape kernel (2 loads + 1 store/thread,
//     1 f32x4/thread, 65536 waves). Loads issued before sincos (hides it).
//     Predict: FETCH/WRITE unchanged; kernel -> 33-36 us if stream shape is
//     the residual limiter; null (e2e +-1 us) => declare ROOFLINE.

#define NVEC (1 << 22)           // total f32x4 output vectors
#define NBLOCKS (NVEC / 256)     // 16384
#define XORV 2048                // qubit-10 flip, in f32x4 units (8192 floats)

typedef __attribute__((ext_vector_type(4))) float f32x4;

__global__ __launch_bounds__(256) void rx_gate_kernel(
    const float* __restrict__ theta,
    const float* __restrict__ re,
    const float* __restrict__ im,
    float* __restrict__ out)
{
    const int v  = blockIdx.x * blockDim.x + threadIdx.x;   // [0, 2^22)
    const int vp = v ^ XORV;                                // partner vector

    // Issue both loads first; sincos computes during load latency.
    const f32x4 r = __builtin_nontemporal_load(reinterpret_cast<const f32x4*>(re) + v);
    const f32x4 i = __builtin_nontemporal_load(reinterpret_cast<const f32x4*>(im) + vp);

    float c[4], s[4];
    {
        const f32x4 th = *reinterpret_cast<const f32x4*>(theta);
        sincosf(0.5f * th.x, &s[0], &c[0]);
        sincosf(0.5f * th.y, &s[1], &c[1]);
        sincosf(0.5f * th.z, &s[2], &c[2]);
        sincosf(0.5f * th.w, &s[3], &c[3]);
    }

    f32x4 o;
    o.x = c[0] * r.x + s[0] * i.x;
    o.y = c[1] * r.y + s[1] * i.y;
    o.z = c[2] * r.z + s[2] * i.z;
    o.w = c[3] * r.w + s[3] * i.w;

    __builtin_nontemporal_store(o, reinterpret_cast<f32x4*>(out) + v);
}

extern "C" void kernel_launch(void* const* d_in, const int* in_sizes, int n_in,
                              void* d_out, int out_size, void* d_ws, size_t ws_size,
                              hipStream_t stream) {
    // setup_inputs order: theta[4], state_re[2^24], state_im[2^24], P[4] (fp32)
    const float* theta = (const float*)d_in[0];
    const float* re    = (const float*)d_in[1];
    const float* im    = (const float*)d_in[2];
    float* out = (float*)d_out;

    rx_gate_kernel<<<NBLOCKS, 256, 0, stream>>>(theta, re, im, out);
}

// Round 7
// 164.780 us; speedup vs baseline: 1.0082x; 1.0082x over previous
//
#include <hip/hip_runtime.h>
#include <math.h>

// RX gate on qubit 10 of a 22-qubit state, batch=4. Output = REAL PART only
// (fp32, 2^24 elems), verified (absmax 0.0156).
//   o0re = c*r0 + s*i1 ; o1re = c*r1 + s*i0   per batch lane.
//
// FINAL (R7): restore of R4, the best harness-verified variant of the
// session (e2e 163.6 us; kernel ~39.5 us, below the 40.4 us harness fill
// dispatches). Session conclusion: ~81% of the 6.29 TB/s copy-ubench
// ceiling on 201 MB combined traffic (134 MB HBM + ~67 MB L3-served);
// FETCH/WRITE at the logical minimum the harness-controlled L3 state
// allows. Three orthogonal structural probes beyond this were null:
//  R2 (4 pairs/thread, 16 MiB k-stride): 41.5 us.
//  R3 (plain loads): 61 us, FETCH UNCHANGED -> L3 residency is harness-set;
//     nt loads = 1.5x throughput via L2-allocation bypass. KEEP nt loads.
//  R4 (1 pair/thread, 32768 waves): ~39.5 us. BEST.
//  R5 (2 pairs/thread, one round trip): ~40 us, null.
//  R6 (copy-shape: 2 loads + 1 store/thread via out[v]=c*re[v]+s*im[v^2048]):
//     e2e 166.1, null/slightly worse. Stream-shape hypothesis refuted.
// Remaining ~19% to copy-rate did not respond to wave count, pairs/thread,
// round-trip depth, or stream shape -> mixed-traffic service-rate ceiling.

#define QC 2048
#define QB 4
#define JSTRIDE (QC * QB)   // 8192 floats between j=0 and j=1 slices
#define NT     (1 << 21)    // total (a,c) pairs == total threads
#define NBLOCKS  (NT / 256) // 8192

typedef __attribute__((ext_vector_type(4))) float f32x4;

__global__ __launch_bounds__(256) void rx_gate_kernel(
    const float* __restrict__ theta,
    const float* __restrict__ re,
    const float* __restrict__ im,
    float* __restrict__ out,
    int out_n)
{
    const int t = blockIdx.x * blockDim.x + threadIdx.x;     // [0, 2^21)

    // theta is wave-uniform (same address) -> scalar load + 4 sincos, once
    float c[QB], s[QB];
    {
        const f32x4 th = *reinterpret_cast<const f32x4*>(theta);
        sincosf(0.5f * th.x, &s[0], &c[0]);
        sincosf(0.5f * th.y, &s[1], &c[1]);
        sincosf(0.5f * th.z, &s[2], &c[2]);
        sincosf(0.5f * th.w, &s[3], &c[3]);
    }

    const int idx0 = (((t >> 11) << 12) | (t & 2047)) * QB;  // j=0 base (16B aligned)
    const int idx1 = idx0 + JSTRIDE;                         // j=1

    const f32x4 r0 = __builtin_nontemporal_load(reinterpret_cast<const f32x4*>(re + idx0));
    const f32x4 i0 = __builtin_nontemporal_load(reinterpret_cast<const f32x4*>(im + idx0));
    const f32x4 r1 = __builtin_nontemporal_load(reinterpret_cast<const f32x4*>(re + idx1));
    const f32x4 i1 = __builtin_nontemporal_load(reinterpret_cast<const f32x4*>(im + idx1));

    f32x4 o0, o1;
    o0.x = c[0] * r0.x + s[0] * i1.x;
    o0.y = c[1] * r0.y + s[1] * i1.y;
    o0.z = c[2] * r0.z + s[2] * i1.z;
    o0.w = c[3] * r0.w + s[3] * i1.w;
    o1.x = c[0] * r1.x + s[0] * i0.x;
    o1.y = c[1] * r1.y + s[1] * i0.y;
    o1.z = c[2] * r1.z + s[2] * i0.z;
    o1.w = c[3] * r1.w + s[3] * i0.w;

    if (idx0 + 3 < out_n)
        __builtin_nontemporal_store(o0, reinterpret_cast<f32x4*>(out + idx0));
    if (idx1 + 3 < out_n)
        __builtin_nontemporal_store(o1, reinterpret_cast<f32x4*>(out + idx1));
}

extern "C" void kernel_launch(void* const* d_in, const int* in_sizes, int n_in,
                              void* d_out, int out_size, void* d_ws, size_t ws_size,
                              hipStream_t stream) {
    // setup_inputs order: theta[4], state_re[2^24], state_im[2^24], P[4] (fp32)
    const float* theta = (const float*)d_in[0];
    const float* re    = (const float*)d_in[1];
    const float* im    = (const float*)d_in[2];
    float* out = (float*)d_out;

    rx_gate_kernel<<<NBLOCKS, 256, 0, stream>>>(theta, re, im, out, out_size);
}